// Round 7
// baseline (485.862 us; speedup 1.0000x reference)
//
#include <hip/hip_runtime.h>
#include <hip/hip_bf16.h>
#include <cfloat>

#define N1C 50176
#define N2C 12544
#define N3C 3136

typedef __attribute__((ext_vector_type(8))) short short8v;
typedef __attribute__((ext_vector_type(4))) float f32x4;

static __device__ __forceinline__ unsigned short f2bf(float f){
  __hip_bfloat16 h = __float2bfloat16(f);
  return *reinterpret_cast<unsigned short*>(&h);
}
static __device__ __forceinline__ float bflo(unsigned v){
  return __uint_as_float(v << 16);
}
static __device__ __forceinline__ float bfhi(unsigned v){
  return __uint_as_float(v & 0xFFFF0000u);
}
static __device__ __forceinline__ float bf2f(unsigned short u){
  return __uint_as_float(((unsigned)u) << 16);
}

// ---------------- transpose x: (16,3,N1) f32 -> xTb (N1, 16, 4) bf16 ----
__global__ __launch_bounds__(256) void transpose_x_kernel(
    const float* __restrict__ x, unsigned short* __restrict__ xTb)
{
  __shared__ float tile[48][65];
  int n0 = blockIdx.x * 64;
  int tid = threadIdx.x;
  int i = tid & 63;
  for (int rr = tid >> 6; rr < 48; rr += 4)
    tile[rr][i] = x[(size_t)rr * N1C + n0 + i];
  __syncthreads();
  for (int j = tid; j < 64*64; j += 256){
    int ii = j >> 6, bc = j & 63, b = bc >> 2, c = bc & 3;
    float v = (c < 3) ? tile[b*3 + c][ii] : 0.f;
    xTb[(size_t)n0 * 64 + j] = f2bf(v);
  }
}

// ---------------- A[n,k,t] = (relu(off @ w1 + b1) @ w2 + b2) ----------------
__global__ __launch_bounds__(256) void compute_A_kernel(
    const float* __restrict__ pos_in, const float* __restrict__ pos_out,
    const int* __restrict__ idx,
    const float* __restrict__ w1, const float* __restrict__ b1,
    const float* __restrict__ w2, const float* __restrict__ b2,
    float* __restrict__ Abuf)
{
  int g = blockIdx.x * 256 + threadIdx.x;
  if (g >= N2C * 9) return;
  int n = g / 9;
  int p = idx[g];
  float o0 = pos_in[2*p]   - pos_out[2*n];
  float o1 = pos_in[2*p+1] - pos_out[2*n+1];
  float A[9];
  #pragma unroll
  for (int t = 0; t < 9; t++) A[t] = b2[t];
  #pragma unroll
  for (int j = 0; j < 16; j++){
    float h = fmaxf(fmaf(o0, w1[j], fmaf(o1, w1[16+j], b1[j])), 0.f);
    #pragma unroll
    for (int t = 0; t < 9; t++) A[t] = fmaf(h, w2[j*9 + t], A[t]);
  }
  #pragma unroll
  for (int t = 0; t < 9; t++) Abuf[(size_t)g*9 + t] = A[t];
}

// ---------------- W (o,k) f32 -> Wb[o][k] bf16, zero-padded to KW --------
__global__ __launch_bounds__(256) void wcvt_kernel(
    const float* __restrict__ W, unsigned short* __restrict__ Wb,
    int total, int K, int KW)
{
  int i = blockIdx.x * 256 + threadIdx.x;
  if (i >= total) return;
  int o = i / KW, k = i % KW;
  Wb[i] = f2bf(k < K ? W[o*K + k] : 0.f);
}

// ======== conv1 path (small CIN) ========
template<int CIN, int CINP, int COUT, int NPB, bool AFFINE>
__global__ __launch_bounds__(256) void conv_mfma_kernel(
    const unsigned short* __restrict__ in, const int* __restrict__ idx,
    const float* __restrict__ Abuf, const unsigned short* __restrict__ Wb,
    const float* __restrict__ bias,
    const float* __restrict__ scale, const float* __restrict__ shift,
    unsigned short* __restrict__ out, float* __restrict__ gpart)
{
  constexpr int K    = CIN * 9;
  constexpr int KW   = (K < 32) ? 32 : K;
  constexpr int KROW = (K < 32) ? 48 : 296;
  constexpr int CHUNKS = KW / 32;
  constexpr int OT   = COUT / 16;
  constexpr int HP   = CINP / 2;
  constexpr int PPT  = 16 * HP;

  __shared__ alignas(16) unsigned short Tb[NPB * 16 * KROW];
  __shared__ float As[NPB * 81];
  __shared__ int   Ip[NPB * 9];
  __shared__ float Sw[4 * COUT];
  __shared__ float Sq[4 * COUT];

  int n0 = blockIdx.x * NPB;
  int tid = threadIdx.x;
  for (int i = tid; i < NPB*81; i += 256) As[i] = Abuf[(size_t)n0*81 + i];
  if (tid < NPB*9) Ip[tid] = idx[n0*9 + tid];
  for (int i = tid; i < 4*COUT; i += 256){ Sw[i] = 0.f; Sq[i] = 0.f; }
  if (K < 32){
    for (int i = tid; i < NPB*16*KROW/2; i += 256) ((unsigned*)Tb)[i] = 0u;
  }
  __syncthreads();

  for (int u = tid; u < NPB*PPT; u += 256){
    int ni = u / PPT, loc = u % PPT;
    int b = loc / HP, c2 = loc % HP;
    const float* As_n = As + ni*81;
    const int*   ip   = Ip + ni*9;
    float scx=1.f, shx=0.f, scy=1.f, shy=0.f;
    if (AFFINE){
      scx = scale[2*c2];   shx = shift[2*c2];
      scy = scale[2*c2+1]; shy = shift[2*c2+1];
    }
    float fx[9], fy[9];
    #pragma unroll
    for (int k = 0; k < 9; k++){
      unsigned v = *(const unsigned*)(in + ((size_t)ip[k]*16 + b)*CINP + 2*c2);
      float x0 = bflo(v), y0 = bfhi(v);
      if (AFFINE){
        x0 = fmaxf(fmaf(x0, scx, shx), 0.f);
        y0 = fmaxf(fmaf(y0, scy, shy), 0.f);
      }
      fx[k] = x0; fy[k] = y0;
    }
    unsigned short e[18];
    #pragma unroll
    for (int t = 0; t < 9; t++){
      float s0 = 0.f, s1 = 0.f;
      #pragma unroll
      for (int k = 0; k < 9; k++){
        float a = As_n[k*9 + t];
        s0 = fmaf(fx[k], a, s0);
        s1 = fmaf(fy[k], a, s1);
      }
      e[t] = f2bf(s0); e[9+t] = f2bf(s1);
    }
    unsigned* dst = (unsigned*)(Tb + (ni*16 + b)*KROW + 18*c2);
    #pragma unroll
    for (int j = 0; j < 9; j++) dst[j] = (unsigned)e[2*j] | ((unsigned)e[2*j+1] << 16);
  }
  __syncthreads();

  int w = tid >> 6, l = tid & 63, lr = l & 15, lg = l >> 4;
  float smr[4] = {0,0,0,0}, sqr[4] = {0,0,0,0};
  int oBase = 0;
  for (int wi = w; wi < NPB*OT; wi += 4){
    int ni = wi / OT, ot = wi % OT;
    oBase = 16*ot + 4*lg;
    f32x4 acc;
    #pragma unroll
    for (int r = 0; r < 4; r++) acc[r] = bias[oBase + r];
    const short8v* ap = (const short8v*)(Wb + (size_t)(16*ot + lr)*KW) + lg;
    const short8v* bp = (const short8v*)(Tb + (ni*16 + lr)*KROW) + lg;
    #pragma unroll
    for (int kk = 0; kk < CHUNKS; kk++)
      acc = __builtin_amdgcn_mfma_f32_16x16x32_bf16(ap[kk*4], bp[kk*4], acc, 0, 0, 0);
    ushort4 o4;
    o4.x = f2bf(acc[0]); o4.y = f2bf(acc[1]); o4.z = f2bf(acc[2]); o4.w = f2bf(acc[3]);
    *(ushort4*)(out + ((size_t)(n0 + ni)*16 + lr)*COUT + oBase) = o4;
    #pragma unroll
    for (int r = 0; r < 4; r++){
      smr[r] += acc[r];
      sqr[r] = fmaf(acc[r], acc[r], sqr[r]);
    }
  }
  #pragma unroll
  for (int m = 1; m < 16; m <<= 1){
    #pragma unroll
    for (int r = 0; r < 4; r++){
      smr[r] += __shfl_xor(smr[r], m);
      sqr[r] += __shfl_xor(sqr[r], m);
    }
  }
  if (lr == 0){
    #pragma unroll
    for (int r = 0; r < 4; r++){
      Sw[w*COUT + oBase + r] = smr[r];
      Sq[w*COUT + oBase + r] = sqr[r];
    }
  }
  __syncthreads();
  for (int o = tid; o < COUT; o += 256){
    float sm = Sw[o] + Sw[COUT + o] + Sw[2*COUT + o] + Sw[3*COUT + o];
    float sq = Sq[o] + Sq[COUT + o] + Sq[2*COUT + o] + Sq[3*COUT + o];
    gpart[(size_t)blockIdx.x * 2*COUT + o] = sm;
    gpart[(size_t)blockIdx.x * 2*COUT + COUT + o] = sq;
  }
}

// ======== conv2/3: wave-per-point, A in per-wave LDS, 2-pass channels ========
// in: (N2, 16, 32) bf16; out: (N2, 16, COUT) bf16. CIN=32, AFFINE.
template<int COUT>
__global__ __launch_bounds__(256, 4) void conv_wave_kernel(
    const unsigned short* __restrict__ in, const int* __restrict__ idx,
    const float* __restrict__ Abuf, const unsigned short* __restrict__ Wb,
    const float* __restrict__ bias,
    const float* __restrict__ scale, const float* __restrict__ shift,
    unsigned short* __restrict__ out, float* __restrict__ gpart)
{
  constexpr int NPB  = 4;
  constexpr int KROW = 288;            // shorts per taps row (36x16B)
  constexpr int AP   = 12;             // A row stride (floats, 16B-mult)
  constexpr int OT   = COUT / 16;

  __shared__ alignas(16) unsigned short Tb[NPB * 16 * KROW];  // 36,864 B
  __shared__ alignas(16) float As[NPB * 9 * AP];              //  1,728 B
  __shared__ float Sw[4 * COUT];
  __shared__ float Sq[4 * COUT];

  int tid = threadIdx.x;
  int w = tid >> 6, l = tid & 63;
  int n0 = blockIdx.x * NPB;

  int nws = __builtin_amdgcn_readfirstlane(n0 + w);

  // cooperative per-wave A load into LDS: A[k][t] at As[w*108 + k*12 + t]
  {
    const float* Ap = Abuf + (size_t)nws * 81;
    float* Aw = As + w * 9 * AP;
    int k = l / 9, t = l - k*9;          // l in [0,64)
    Aw[k*AP + t] = Ap[l];
    if (l < 17){
      int j = l + 64;
      int k2 = j / 9, t2 = j - k2*9;
      Aw[k2*AP + t2] = Ap[j];
    }
  }
  int ip[9];
  {
    const int* ipr = idx + nws * 9;
    #pragma unroll
    for (int k = 0; k < 9; k++) ip[k] = ipr[k];
  }

  // ---- phase 2: lane = (b, 8-channel group); 9x dwordx4 gather ----
  int b = l & 15, cg = l >> 4;
  float4 scA = *(const float4*)(scale + cg*8);
  float4 scB = *(const float4*)(scale + cg*8 + 4);
  float4 shA = *(const float4*)(shift + cg*8);
  float4 shB = *(const float4*)(shift + cg*8 + 4);

  uint4 rv[9];
  #pragma unroll
  for (int k = 0; k < 9; k++){
    const unsigned short* rp = in + (size_t)ip[k]*512 + b*32 + cg*8;
    rv[k] = *(const uint4*)rp;
  }

  const float* Aw = As + w * 9 * AP;

  // two half-passes of 4 channels: acc[36] live; A rows broadcast from LDS
  #pragma unroll
  for (int h = 0; h < 2; h++){
    float sc[4], sh[4];
    if (h == 0){
      sc[0]=scA.x; sc[1]=scA.y; sc[2]=scA.z; sc[3]=scA.w;
      sh[0]=shA.x; sh[1]=shA.y; sh[2]=shA.z; sh[3]=shA.w;
    } else {
      sc[0]=scB.x; sc[1]=scB.y; sc[2]=scB.z; sc[3]=scB.w;
      sh[0]=shB.x; sh[1]=shB.y; sh[2]=shB.z; sh[3]=shB.w;
    }
    float acc[36];
    #pragma unroll
    for (int i = 0; i < 36; i++) acc[i] = 0.f;
    #pragma unroll
    for (int k = 0; k < 9; k++){
      unsigned u0 = (h == 0) ? rv[k].x : rv[k].z;
      unsigned u1 = (h == 0) ? rv[k].y : rv[k].w;
      float c0 = fmaxf(fmaf(bflo(u0), sc[0], sh[0]), 0.f);
      float c1 = fmaxf(fmaf(bfhi(u0), sc[1], sh[1]), 0.f);
      float c2 = fmaxf(fmaf(bflo(u1), sc[2], sh[2]), 0.f);
      float c3 = fmaxf(fmaf(bfhi(u1), sc[3], sh[3]), 0.f);
      f32x4 a03 = *(const f32x4*)(Aw + k*AP);      // ds_read_b128 (broadcast)
      f32x4 a47 = *(const f32x4*)(Aw + k*AP + 4);  // ds_read_b128 (broadcast)
      float a8  = Aw[k*AP + 8];
      float ar[9] = {a03[0],a03[1],a03[2],a03[3],a47[0],a47[1],a47[2],a47[3],a8};
      #pragma unroll
      for (int t = 0; t < 9; t++){
        float a = ar[t];
        acc[t]      = fmaf(c0, a, acc[t]);
        acc[9 + t]  = fmaf(c1, a, acc[9 + t]);
        acc[18 + t] = fmaf(c2, a, acc[18 + t]);
        acc[27 + t] = fmaf(c3, a, acc[27 + t]);
      }
    }
    // pack 36 f32 -> 36 bf16 (72 B), 9x ds_write_b64
    uint2* du = (uint2*)(Tb + (size_t)(w*16 + b)*KROW + cg*72 + h*36);
    #pragma unroll
    for (int q = 0; q < 9; q++){
      uint2 o;
      o.x = (unsigned)f2bf(acc[4*q+0]) | ((unsigned)f2bf(acc[4*q+1]) << 16);
      o.y = (unsigned)f2bf(acc[4*q+2]) | ((unsigned)f2bf(acc[4*q+3]) << 16);
      du[q] = o;
    }
  }

  // ---- phase 3: wave-local (ni = w), no block barrier needed ----
  int lr = l & 15, lg = l >> 4;
  const short8v* bp = (const short8v*)(Tb + (size_t)(w*16 + lr)*KROW) + lg;
  #pragma unroll
  for (int ot = 0; ot < OT; ot++){
    int oBase = 16*ot + 4*lg;
    f32x4 a3;
    #pragma unroll
    for (int r = 0; r < 4; r++) a3[r] = bias[oBase + r];
    const short8v* ap = (const short8v*)(Wb + (size_t)(16*ot + lr)*288) + lg;
    #pragma unroll
    for (int kk = 0; kk < 9; kk++)
      a3 = __builtin_amdgcn_mfma_f32_16x16x32_bf16(ap[kk*4], bp[kk*4], a3, 0, 0, 0);
    ushort4 o4;
    o4.x = f2bf(a3[0]); o4.y = f2bf(a3[1]); o4.z = f2bf(a3[2]); o4.w = f2bf(a3[3]);
    *(ushort4*)(out + ((size_t)(n0 + w)*16 + lr)*COUT + oBase) = o4;

    float smr[4], sqr[4];
    #pragma unroll
    for (int r = 0; r < 4; r++){ smr[r] = a3[r]; sqr[r] = a3[r]*a3[r]; }
    #pragma unroll
    for (int m = 1; m < 16; m <<= 1){
      #pragma unroll
      for (int r = 0; r < 4; r++){
        smr[r] += __shfl_xor(smr[r], m);
        sqr[r] += __shfl_xor(sqr[r], m);
      }
    }
    if (lr == 0){
      #pragma unroll
      for (int r = 0; r < 4; r++){
        Sw[w*COUT + oBase + r] = smr[r];
        Sq[w*COUT + oBase + r] = sqr[r];
      }
    }
  }
  __syncthreads();
  for (int o = tid; o < COUT; o += 256){
    float sm = Sw[o] + Sw[COUT + o] + Sw[2*COUT + o] + Sw[3*COUT + o];
    float sq = Sq[o] + Sq[COUT + o] + Sq[2*COUT + o] + Sq[3*COUT + o];
    gpart[(size_t)blockIdx.x * 2*COUT + o] = sm;
    gpart[(size_t)blockIdx.x * 2*COUT + COUT + o] = sq;
  }
}

// ---------------- finalize BN ----------------
__global__ __launch_bounds__(256) void bn_finalize_kernel(
    const float* __restrict__ gpart, int NB, int C,
    const float* __restrict__ g, const float* __restrict__ bb,
    float* __restrict__ sc, float* __restrict__ sh, float invN)
{
  int c = blockIdx.x;
  float sm = 0.f, sq = 0.f;
  for (int i = threadIdx.x; i < NB; i += 256){
    sm += gpart[(size_t)i*2*C + c];
    sq += gpart[(size_t)i*2*C + C + c];
  }
  #pragma unroll
  for (int off = 32; off > 0; off >>= 1){
    sm += __shfl_down(sm, off);
    sq += __shfl_down(sq, off);
  }
  __shared__ float rs[8];
  int wd = threadIdx.x >> 6, ln = threadIdx.x & 63;
  if (ln == 0){ rs[wd] = sm; rs[4+wd] = sq; }
  __syncthreads();
  if (threadIdx.x == 0){
    float S = rs[0]+rs[1]+rs[2]+rs[3], Q = rs[4]+rs[5]+rs[6]+rs[7];
    float mean = S * invN;
    float var  = fmaxf(Q * invN - mean*mean, 0.f);
    float s = g[c] * rsqrtf(var + 1e-5f);
    sc[c] = s;
    sh[c] = bb[c] - mean * s;
  }
}

// ------------- BN3 + relu + max-pool + write (16,64,N3) f32 -------------
__global__ __launch_bounds__(256) void pool_kernel(
    const unsigned short* __restrict__ h3, const int* __restrict__ pidx,
    const float* __restrict__ sc, const float* __restrict__ sh,
    float* __restrict__ out)
{
  __shared__ float P[16][1024];
  int m0 = blockIdx.x * 16;
  int tid = threadIdx.x;
  for (int mi = 0; mi < 16; mi++){
    int m = m0 + mi;
    int p0 = pidx[m*4+0], p1 = pidx[m*4+1], p2 = pidx[m*4+2], p3 = pidx[m*4+3];
    #pragma unroll
    for (int q = 0; q < 4; q++){
      int bo = tid + q*256;
      int o = bo & 63;
      float s = sc[o], h = sh[o];
      float v0 = fmaf(bf2f(h3[(size_t)p0*1024 + bo]), s, h);
      float v1 = fmaf(bf2f(h3[(size_t)p1*1024 + bo]), s, h);
      float v2 = fmaf(bf2f(h3[(size_t)p2*1024 + bo]), s, h);
      float v3 = fmaf(bf2f(h3[(size_t)p3*1024 + bo]), s, h);
      P[mi][bo] = fmaxf(fmaxf(fmaxf(v0,v1), fmaxf(v2,v3)), 0.f);
    }
  }
  __syncthreads();
  #pragma unroll
  for (int w = 0; w < 4; w++){
    int r = tid + w*256;
    float* dst = out + (size_t)r*N3C + m0;
    #pragma unroll
    for (int mi = 0; mi < 16; mi++) dst[mi] = P[mi][r];
  }
}

// ---------------- launch ----------------
extern "C" void kernel_launch(void* const* d_in, const int* in_sizes, int n_in,
                              void* d_out, int out_size, void* d_ws, size_t ws_size,
                              hipStream_t stream)
{
  const float* x    = (const float*)d_in[0];
  const float* l1   = (const float*)d_in[1];
  const float* l2   = (const float*)d_in[2];
  const int* knn1   = (const int*)d_in[4];
  const int* knn2   = (const int*)d_in[5];
  const int* knn3   = (const int*)d_in[6];
  const int* pidx   = (const int*)d_in[7];

  const float* c1_w1 = (const float*)d_in[8];
  const float* c1_b1 = (const float*)d_in[9];
  const float* c1_w2 = (const float*)d_in[10];
  const float* c1_b2 = (const float*)d_in[11];
  const float* c1_k  = (const float*)d_in[12];
  const float* c1_bs = (const float*)d_in[13];
  const float* c2_w1 = (const float*)d_in[14];
  const float* c2_b1 = (const float*)d_in[15];
  const float* c2_w2 = (const float*)d_in[16];
  const float* c2_b2 = (const float*)d_in[17];
  const float* c2_k  = (const float*)d_in[18];
  const float* c2_bs = (const float*)d_in[19];
  const float* c3_w1 = (const float*)d_in[20];
  const float* c3_b1 = (const float*)d_in[21];
  const float* c3_w2 = (const float*)d_in[22];
  const float* c3_b2 = (const float*)d_in[23];
  const float* c3_k  = (const float*)d_in[24];
  const float* c3_bs = (const float*)d_in[25];
  const float* bn1_g = (const float*)d_in[26];
  const float* bn1_b = (const float*)d_in[27];
  const float* bn2_g = (const float*)d_in[28];
  const float* bn2_b = (const float*)d_in[29];
  const float* bn3_g = (const float*)d_in[30];
  const float* bn3_b = (const float*)d_in[31];

  char* ws = (char*)d_ws;
  unsigned short* xTb = (unsigned short*)(ws + 0);
  unsigned short* h1  = (unsigned short*)(ws + 6422528);
  unsigned short* h2  = (unsigned short*)(ws + 19267584);
  unsigned short* h3  = (unsigned short*)(ws + 32112640);
  float* Abuf         = (float*)(ws + 57802752);
  float* gpart        = (float*)(ws + 61867008);
  unsigned short* wb1 = (unsigned short*)(ws + 65078272);
  unsigned short* wb2 = (unsigned short*)(ws + 65081344);
  unsigned short* wb3 = (unsigned short*)(ws + 65099776);
  float* sc1 = (float*)(ws + 65137664); float* sh1 = sc1 + 32;
  float* sc2 = sh1 + 32;                float* sh2 = sc2 + 32;
  float* sc3 = sh2 + 32;                float* sh3 = sc3 + 64;

  const float invN = 1.0f / (float)(N2C * 16);
  const int ablocks = (N2C * 9 + 255) / 256;

  transpose_x_kernel<<<N1C/64, 256, 0, stream>>>(x, xTb);
  wcvt_kernel<<<(32*32 + 255)/256, 256, 0, stream>>>(c1_k, wb1, 32*32, 27, 32);
  wcvt_kernel<<<(32*288 + 255)/256, 256, 0, stream>>>(c2_k, wb2, 32*288, 288, 288);
  wcvt_kernel<<<(64*288 + 255)/256, 256, 0, stream>>>(c3_k, wb3, 64*288, 288, 288);

  // conv1
  compute_A_kernel<<<ablocks, 256, 0, stream>>>(l1, l2, knn1, c1_w1, c1_b1, c1_w2, c1_b2, Abuf);
  conv_mfma_kernel<3, 4, 32, 8, false><<<N2C/8, 256, 0, stream>>>(
      xTb, knn1, Abuf, wb1, c1_bs, nullptr, nullptr, h1, gpart);
  bn_finalize_kernel<<<32, 256, 0, stream>>>(gpart, N2C/8, 32, bn1_g, bn1_b, sc1, sh1, invN);

  // conv2
  compute_A_kernel<<<ablocks, 256, 0, stream>>>(l2, l2, knn2, c2_w1, c2_b1, c2_w2, c2_b2, Abuf);
  conv_wave_kernel<32><<<N2C/4, 256, 0, stream>>>(
      h1, knn2, Abuf, wb2, c2_bs, sc1, sh1, h2, gpart);
  bn_finalize_kernel<<<32, 256, 0, stream>>>(gpart, N2C/4, 32, bn2_g, bn2_b, sc2, sh2, invN);

  // conv3
  compute_A_kernel<<<ablocks, 256, 0, stream>>>(l2, l2, knn3, c3_w1, c3_b1, c3_w2, c3_b2, Abuf);
  conv_wave_kernel<64><<<N2C/4, 256, 0, stream>>>(
      h2, knn3, Abuf, wb3, c3_bs, sc2, sh2, h3, gpart);
  bn_finalize_kernel<<<64, 256, 0, stream>>>(gpart, N2C/4, 64, bn3_g, bn3_b, sc3, sh3, invN);

  pool_kernel<<<N3C/16, 256, 0, stream>>>(h3, pidx, sc3, sh3, (float*)d_out);
}

// Round 8
// 160.868 us; speedup vs baseline: 3.0203x; 3.0203x over previous
//
#include <hip/hip_runtime.h>
#include <hip/hip_bf16.h>
#include <cfloat>

#define N1C 50176
#define N2C 12544
#define N3C 3136

typedef __attribute__((ext_vector_type(8))) short short8v;
typedef __attribute__((ext_vector_type(4))) float f32x4;

static __device__ __forceinline__ unsigned short f2bf(float f){
  __hip_bfloat16 h = __float2bfloat16(f);
  return *reinterpret_cast<unsigned short*>(&h);
}
static __device__ __forceinline__ float bflo(unsigned v){
  return __uint_as_float(v << 16);
}
static __device__ __forceinline__ float bfhi(unsigned v){
  return __uint_as_float(v & 0xFFFF0000u);
}
static __device__ __forceinline__ float bf2f(unsigned short u){
  return __uint_as_float(((unsigned)u) << 16);
}
static __device__ __forceinline__ unsigned pk2(float a, float b){
  return (unsigned)f2bf(a) | ((unsigned)f2bf(b) << 16);
}

// ---------------- transpose x: (16,3,N1) f32 -> xTb (N1, 16, 4) bf16 ----
__global__ __launch_bounds__(256) void transpose_x_kernel(
    const float* __restrict__ x, unsigned short* __restrict__ xTb)
{
  __shared__ float tile[48][65];
  int n0 = blockIdx.x * 64;
  int tid = threadIdx.x;
  int i = tid & 63;
  for (int rr = tid >> 6; rr < 48; rr += 4)
    tile[rr][i] = x[(size_t)rr * N1C + n0 + i];
  __syncthreads();
  for (int j = tid; j < 64*64; j += 256){
    int ii = j >> 6, bc = j & 63, b = bc >> 2, c = bc & 3;
    float v = (c < 3) ? tile[b*3 + c][ii] : 0.f;
    xTb[(size_t)n0 * 64 + j] = f2bf(v);
  }
}

// ---------------- A[n,k,t] = (relu(off @ w1 + b1) @ w2 + b2) ----------------
__global__ __launch_bounds__(256) void compute_A_kernel(
    const float* __restrict__ pos_in, const float* __restrict__ pos_out,
    const int* __restrict__ idx,
    const float* __restrict__ w1, const float* __restrict__ b1,
    const float* __restrict__ w2, const float* __restrict__ b2,
    float* __restrict__ Abuf)
{
  int g = blockIdx.x * 256 + threadIdx.x;
  if (g >= N2C * 9) return;
  int n = g / 9;
  int p = idx[g];
  float o0 = pos_in[2*p]   - pos_out[2*n];
  float o1 = pos_in[2*p+1] - pos_out[2*n+1];
  float A[9];
  #pragma unroll
  for (int t = 0; t < 9; t++) A[t] = b2[t];
  #pragma unroll
  for (int j = 0; j < 16; j++){
    float h = fmaxf(fmaf(o0, w1[j], fmaf(o1, w1[16+j], b1[j])), 0.f);
    #pragma unroll
    for (int t = 0; t < 9; t++) A[t] = fmaf(h, w2[j*9 + t], A[t]);
  }
  #pragma unroll
  for (int t = 0; t < 9; t++) Abuf[(size_t)g*9 + t] = A[t];
}

// ------ W (o,c,t) f32 -> Wb bf16. mode0: Wb[o][k=c*9+t] pad to KW.
// ------ mode1: Wb[o][k'=t*32+c] (t-major permutation, K=KW=288).
__global__ __launch_bounds__(256) void wcvt_kernel(
    const float* __restrict__ W, unsigned short* __restrict__ Wb,
    int total, int K, int KW, int mode)
{
  int i = blockIdx.x * 256 + threadIdx.x;
  if (i >= total) return;
  int o = i / KW, r = i % KW;
  float v;
  if (mode == 0){
    v = (r < K) ? W[o*K + r] : 0.f;
  } else {
    int t = r >> 5, c = r & 31;          // r = t*32 + c
    v = W[o*288 + c*9 + t];
  }
  Wb[i] = f2bf(v);
}

// ======== conv1 path (small CIN), linear k-layout ========
template<int CIN, int CINP, int COUT, int NPB, bool AFFINE>
__global__ __launch_bounds__(256) void conv_mfma_kernel(
    const unsigned short* __restrict__ in, const int* __restrict__ idx,
    const float* __restrict__ Abuf, const unsigned short* __restrict__ Wb,
    const float* __restrict__ bias,
    const float* __restrict__ scale, const float* __restrict__ shift,
    unsigned short* __restrict__ out, float* __restrict__ gpart)
{
  constexpr int K    = CIN * 9;
  constexpr int KW   = (K < 32) ? 32 : K;
  constexpr int KROW = (K < 32) ? 48 : 296;
  constexpr int CHUNKS = KW / 32;
  constexpr int OT   = COUT / 16;
  constexpr int HP   = CINP / 2;
  constexpr int PPT  = 16 * HP;

  __shared__ alignas(16) unsigned short Tb[NPB * 16 * KROW];
  __shared__ float As[NPB * 81];
  __shared__ int   Ip[NPB * 9];
  __shared__ float Sw[4 * COUT];
  __shared__ float Sq[4 * COUT];

  int n0 = blockIdx.x * NPB;
  int tid = threadIdx.x;
  for (int i = tid; i < NPB*81; i += 256) As[i] = Abuf[(size_t)n0*81 + i];
  if (tid < NPB*9) Ip[tid] = idx[n0*9 + tid];
  for (int i = tid; i < 4*COUT; i += 256){ Sw[i] = 0.f; Sq[i] = 0.f; }
  if (K < 32){
    for (int i = tid; i < NPB*16*KROW/2; i += 256) ((unsigned*)Tb)[i] = 0u;
  }
  __syncthreads();

  for (int u = tid; u < NPB*PPT; u += 256){
    int ni = u / PPT, loc = u % PPT;
    int b = loc / HP, c2 = loc % HP;
    const float* As_n = As + ni*81;
    const int*   ip   = Ip + ni*9;
    float scx=1.f, shx=0.f, scy=1.f, shy=0.f;
    if (AFFINE){
      scx = scale[2*c2];   shx = shift[2*c2];
      scy = scale[2*c2+1]; shy = shift[2*c2+1];
    }
    float fx[9], fy[9];
    #pragma unroll
    for (int k = 0; k < 9; k++){
      unsigned v = *(const unsigned*)(in + ((size_t)ip[k]*16 + b)*CINP + 2*c2);
      float x0 = bflo(v), y0 = bfhi(v);
      if (AFFINE){
        x0 = fmaxf(fmaf(x0, scx, shx), 0.f);
        y0 = fmaxf(fmaf(y0, scy, shy), 0.f);
      }
      fx[k] = x0; fy[k] = y0;
    }
    unsigned short e[18];
    #pragma unroll
    for (int t = 0; t < 9; t++){
      float s0 = 0.f, s1 = 0.f;
      #pragma unroll
      for (int k = 0; k < 9; k++){
        float a = As_n[k*9 + t];
        s0 = fmaf(fx[k], a, s0);
        s1 = fmaf(fy[k], a, s1);
      }
      e[t] = f2bf(s0); e[9+t] = f2bf(s1);
    }
    unsigned* dst = (unsigned*)(Tb + (ni*16 + b)*KROW + 18*c2);
    #pragma unroll
    for (int j = 0; j < 9; j++) dst[j] = (unsigned)e[2*j] | ((unsigned)e[2*j+1] << 16);
  }
  __syncthreads();

  int w = tid >> 6, l = tid & 63, lr = l & 15, lg = l >> 4;
  float smr[4] = {0,0,0,0}, sqr[4] = {0,0,0,0};
  int oBase = 0;
  for (int wi = w; wi < NPB*OT; wi += 4){
    int ni = wi / OT, ot = wi % OT;
    oBase = 16*ot + 4*lg;
    f32x4 acc;
    #pragma unroll
    for (int r = 0; r < 4; r++) acc[r] = bias[oBase + r];
    const short8v* ap = (const short8v*)(Wb + (size_t)(16*ot + lr)*KW) + lg;
    const short8v* bp = (const short8v*)(Tb + (ni*16 + lr)*KROW) + lg;
    #pragma unroll
    for (int kk = 0; kk < CHUNKS; kk++)
      acc = __builtin_amdgcn_mfma_f32_16x16x32_bf16(ap[kk*4], bp[kk*4], acc, 0, 0, 0);
    ushort4 o4;
    o4.x = f2bf(acc[0]); o4.y = f2bf(acc[1]); o4.z = f2bf(acc[2]); o4.w = f2bf(acc[3]);
    *(ushort4*)(out + ((size_t)(n0 + ni)*16 + lr)*COUT + oBase) = o4;
    #pragma unroll
    for (int r = 0; r < 4; r++){
      smr[r] += acc[r];
      sqr[r] = fmaf(acc[r], acc[r], sqr[r]);
    }
  }
  #pragma unroll
  for (int m = 1; m < 16; m <<= 1){
    #pragma unroll
    for (int r = 0; r < 4; r++){
      smr[r] += __shfl_xor(smr[r], m);
      sqr[r] += __shfl_xor(sqr[r], m);
    }
  }
  if (lr == 0){
    #pragma unroll
    for (int r = 0; r < 4; r++){
      Sw[w*COUT + oBase + r] = smr[r];
      Sq[w*COUT + oBase + r] = sqr[r];
    }
  }
  __syncthreads();
  for (int o = tid; o < COUT; o += 256){
    float sm = Sw[o] + Sw[COUT + o] + Sw[2*COUT + o] + Sw[3*COUT + o];
    float sq = Sq[o] + Sq[COUT + o] + Sq[2*COUT + o] + Sq[3*COUT + o];
    gpart[(size_t)blockIdx.x * 2*COUT + o] = sm;
    gpart[(size_t)blockIdx.x * 2*COUT + COUT + o] = sq;
  }
}

// ======== conv2/3: wave-per-point, named-vector accs, t-major k-layout ========
// in: (N2, 16, 32) bf16; out: (N2, 16, COUT) bf16. CIN=32, AFFINE.
template<int COUT>
__global__ __launch_bounds__(256, 4) void conv_wave_kernel(
    const unsigned short* __restrict__ in, const int* __restrict__ idx,
    const float* __restrict__ Abuf, const unsigned short* __restrict__ Wb,
    const float* __restrict__ bias,
    const float* __restrict__ scale, const float* __restrict__ shift,
    unsigned short* __restrict__ out, float* __restrict__ gpart)
{
  constexpr int NPB  = 4;
  constexpr int KROW = 296;            // shorts per taps row (592B, 20-bank stagger)
  constexpr int OT   = COUT / 16;

  __shared__ alignas(16) unsigned short Tb[NPB * 16 * KROW];  // 37,888 B
  __shared__ float Sw[4 * COUT];
  __shared__ float Sq[4 * COUT];

  int tid = threadIdx.x;
  int w = tid >> 6, l = tid & 63;
  int n0 = blockIdx.x * NPB;

  int nws = __builtin_amdgcn_readfirstlane(n0 + w);

  // A (wave-uniform address -> scalar loads)
  float areg[81];
  {
    const float* Ap = Abuf + (size_t)nws * 81;
    #pragma unroll
    for (int j = 0; j < 81; j++) areg[j] = Ap[j];
  }
  int ip[9];
  {
    const int* ipr = idx + nws * 9;
    #pragma unroll
    for (int k = 0; k < 9; k++) ip[k] = ipr[k];
  }

  // ---- phase 2: lane = (b, 8-channel group); 9x dwordx4 gather ----
  int b = l & 15, cg = l >> 4;
  float4 scA = *(const float4*)(scale + cg*8);
  float4 scB = *(const float4*)(scale + cg*8 + 4);
  float4 shA = *(const float4*)(shift + cg*8);
  float4 shB = *(const float4*)(shift + cg*8 + 4);

  uint4 rv[9];
  #pragma unroll
  for (int k = 0; k < 9; k++){
    const unsigned short* rp = in + (size_t)ip[k]*512 + b*32 + cg*8;
    rv[k] = *(const uint4*)rp;
  }

  // two half-passes of 4 channels; acc = nine NAMED f32x4 (t-indexed, c in lanes)
  unsigned short* drow = Tb + (size_t)(w*16 + b)*KROW + cg*8;
  #pragma unroll
  for (int h = 0; h < 2; h++){
    f32x4 sc4, sh4;
    if (h == 0){
      sc4[0]=scA.x; sc4[1]=scA.y; sc4[2]=scA.z; sc4[3]=scA.w;
      sh4[0]=shA.x; sh4[1]=shA.y; sh4[2]=shA.z; sh4[3]=shA.w;
    } else {
      sc4[0]=scB.x; sc4[1]=scB.y; sc4[2]=scB.z; sc4[3]=scB.w;
      sh4[0]=shB.x; sh4[1]=shB.y; sh4[2]=shB.z; sh4[3]=shB.w;
    }
    f32x4 tv0={0,0,0,0}, tv1={0,0,0,0}, tv2={0,0,0,0}, tv3={0,0,0,0},
          tv4={0,0,0,0}, tv5={0,0,0,0}, tv6={0,0,0,0}, tv7={0,0,0,0},
          tv8={0,0,0,0};
    #pragma unroll
    for (int k = 0; k < 9; k++){
      unsigned u0 = (h == 0) ? rv[k].x : rv[k].z;
      unsigned u1 = (h == 0) ? rv[k].y : rv[k].w;
      f32x4 f;
      f[0] = bflo(u0); f[1] = bfhi(u0); f[2] = bflo(u1); f[3] = bfhi(u1);
      f = f * sc4 + sh4;
      f[0] = fmaxf(f[0], 0.f); f[1] = fmaxf(f[1], 0.f);
      f[2] = fmaxf(f[2], 0.f); f[3] = fmaxf(f[3], 0.f);
      tv0 += f * areg[k*9 + 0];
      tv1 += f * areg[k*9 + 1];
      tv2 += f * areg[k*9 + 2];
      tv3 += f * areg[k*9 + 3];
      tv4 += f * areg[k*9 + 4];
      tv5 += f * areg[k*9 + 5];
      tv6 += f * areg[k*9 + 6];
      tv7 += f * areg[k*9 + 7];
      tv8 += f * areg[k*9 + 8];
    }
    // pack: k' = t*32 + (cg*8 + h*4 + c); one uint2 per t straight from tv_t
    unsigned short* dh = drow + h*4;
    { uint2 o; o.x = pk2(tv0[0],tv0[1]); o.y = pk2(tv0[2],tv0[3]); *(uint2*)(dh + 0*32) = o; }
    { uint2 o; o.x = pk2(tv1[0],tv1[1]); o.y = pk2(tv1[2],tv1[3]); *(uint2*)(dh + 1*32) = o; }
    { uint2 o; o.x = pk2(tv2[0],tv2[1]); o.y = pk2(tv2[2],tv2[3]); *(uint2*)(dh + 2*32) = o; }
    { uint2 o; o.x = pk2(tv3[0],tv3[1]); o.y = pk2(tv3[2],tv3[3]); *(uint2*)(dh + 3*32) = o; }
    { uint2 o; o.x = pk2(tv4[0],tv4[1]); o.y = pk2(tv4[2],tv4[3]); *(uint2*)(dh + 4*32) = o; }
    { uint2 o; o.x = pk2(tv5[0],tv5[1]); o.y = pk2(tv5[2],tv5[3]); *(uint2*)(dh + 5*32) = o; }
    { uint2 o; o.x = pk2(tv6[0],tv6[1]); o.y = pk2(tv6[2],tv6[3]); *(uint2*)(dh + 6*32) = o; }
    { uint2 o; o.x = pk2(tv7[0],tv7[1]); o.y = pk2(tv7[2],tv7[3]); *(uint2*)(dh + 7*32) = o; }
    { uint2 o; o.x = pk2(tv8[0],tv8[1]); o.y = pk2(tv8[2],tv8[3]); *(uint2*)(dh + 8*32) = o; }
  }

  // ---- phase 3: wave-local (ni = w), no block barrier needed ----
  int lr = l & 15, lg = l >> 4;
  const short8v* bp = (const short8v*)(Tb + (size_t)(w*16 + lr)*KROW) + lg;
  #pragma unroll
  for (int ot = 0; ot < OT; ot++){
    int oBase = 16*ot + 4*lg;
    f32x4 a3;
    #pragma unroll
    for (int r = 0; r < 4; r++) a3[r] = bias[oBase + r];
    const short8v* ap = (const short8v*)(Wb + (size_t)(16*ot + lr)*288) + lg;
    #pragma unroll
    for (int kk = 0; kk < 9; kk++)
      a3 = __builtin_amdgcn_mfma_f32_16x16x32_bf16(ap[kk*4], bp[kk*4], a3, 0, 0, 0);
    ushort4 o4;
    o4.x = f2bf(a3[0]); o4.y = f2bf(a3[1]); o4.z = f2bf(a3[2]); o4.w = f2bf(a3[3]);
    *(ushort4*)(out + ((size_t)(n0 + w)*16 + lr)*COUT + oBase) = o4;

    float smr[4], sqr[4];
    #pragma unroll
    for (int r = 0; r < 4; r++){ smr[r] = a3[r]; sqr[r] = a3[r]*a3[r]; }
    #pragma unroll
    for (int m = 1; m < 16; m <<= 1){
      #pragma unroll
      for (int r = 0; r < 4; r++){
        smr[r] += __shfl_xor(smr[r], m);
        sqr[r] += __shfl_xor(sqr[r], m);
      }
    }
    if (lr == 0){
      #pragma unroll
      for (int r = 0; r < 4; r++){
        Sw[w*COUT + oBase + r] = smr[r];
        Sq[w*COUT + oBase + r] = sqr[r];
      }
    }
  }
  __syncthreads();
  for (int o = tid; o < COUT; o += 256){
    float sm = Sw[o] + Sw[COUT + o] + Sw[2*COUT + o] + Sw[3*COUT + o];
    float sq = Sq[o] + Sq[COUT + o] + Sq[2*COUT + o] + Sq[3*COUT + o];
    gpart[(size_t)blockIdx.x * 2*COUT + o] = sm;
    gpart[(size_t)blockIdx.x * 2*COUT + COUT + o] = sq;
  }
}

// ---------------- finalize BN ----------------
__global__ __launch_bounds__(256) void bn_finalize_kernel(
    const float* __restrict__ gpart, int NB, int C,
    const float* __restrict__ g, const float* __restrict__ bb,
    float* __restrict__ sc, float* __restrict__ sh, float invN)
{
  int c = blockIdx.x;
  float sm = 0.f, sq = 0.f;
  for (int i = threadIdx.x; i < NB; i += 256){
    sm += gpart[(size_t)i*2*C + c];
    sq += gpart[(size_t)i*2*C + C + c];
  }
  #pragma unroll
  for (int off = 32; off > 0; off >>= 1){
    sm += __shfl_down(sm, off);
    sq += __shfl_down(sq, off);
  }
  __shared__ float rs[8];
  int wd = threadIdx.x >> 6, ln = threadIdx.x & 63;
  if (ln == 0){ rs[wd] = sm; rs[4+wd] = sq; }
  __syncthreads();
  if (threadIdx.x == 0){
    float S = rs[0]+rs[1]+rs[2]+rs[3], Q = rs[4]+rs[5]+rs[6]+rs[7];
    float mean = S * invN;
    float var  = fmaxf(Q * invN - mean*mean, 0.f);
    float s = g[c] * rsqrtf(var + 1e-5f);
    sc[c] = s;
    sh[c] = bb[c] - mean * s;
  }
}

// ------------- BN3 + relu + max-pool + write (16,64,N3) f32 -------------
__global__ __launch_bounds__(256) void pool_kernel(
    const unsigned short* __restrict__ h3, const int* __restrict__ pidx,
    const float* __restrict__ sc, const float* __restrict__ sh,
    float* __restrict__ out)
{
  __shared__ float P[16][1024];
  int m0 = blockIdx.x * 16;
  int tid = threadIdx.x;
  for (int mi = 0; mi < 16; mi++){
    int m = m0 + mi;
    int p0 = pidx[m*4+0], p1 = pidx[m*4+1], p2 = pidx[m*4+2], p3 = pidx[m*4+3];
    #pragma unroll
    for (int q = 0; q < 4; q++){
      int bo = tid + q*256;
      int o = bo & 63;
      float s = sc[o], h = sh[o];
      float v0 = fmaf(bf2f(h3[(size_t)p0*1024 + bo]), s, h);
      float v1 = fmaf(bf2f(h3[(size_t)p1*1024 + bo]), s, h);
      float v2 = fmaf(bf2f(h3[(size_t)p2*1024 + bo]), s, h);
      float v3 = fmaf(bf2f(h3[(size_t)p3*1024 + bo]), s, h);
      P[mi][bo] = fmaxf(fmaxf(fmaxf(v0,v1), fmaxf(v2,v3)), 0.f);
    }
  }
  __syncthreads();
  #pragma unroll
  for (int w = 0; w < 4; w++){
    int r = tid + w*256;
    float* dst = out + (size_t)r*N3C + m0;
    #pragma unroll
    for (int mi = 0; mi < 16; mi++) dst[mi] = P[mi][r];
  }
}

// ---------------- launch ----------------
extern "C" void kernel_launch(void* const* d_in, const int* in_sizes, int n_in,
                              void* d_out, int out_size, void* d_ws, size_t ws_size,
                              hipStream_t stream)
{
  const float* x    = (const float*)d_in[0];
  const float* l1   = (const float*)d_in[1];
  const float* l2   = (const float*)d_in[2];
  const int* knn1   = (const int*)d_in[4];
  const int* knn2   = (const int*)d_in[5];
  const int* knn3   = (const int*)d_in[6];
  const int* pidx   = (const int*)d_in[7];

  const float* c1_w1 = (const float*)d_in[8];
  const float* c1_b1 = (const float*)d_in[9];
  const float* c1_w2 = (const float*)d_in[10];
  const float* c1_b2 = (const float*)d_in[11];
  const float* c1_k  = (const float*)d_in[12];
  const float* c1_bs = (const float*)d_in[13];
  const float* c2_w1 = (const float*)d_in[14];
  const float* c2_b1 = (const float*)d_in[15];
  const float* c2_w2 = (const float*)d_in[16];
  const float* c2_b2 = (const float*)d_in[17];
  const float* c2_k  = (const float*)d_in[18];
  const float* c2_bs = (const float*)d_in[19];
  const float* c3_w1 = (const float*)d_in[20];
  const float* c3_b1 = (const float*)d_in[21];
  const float* c3_w2 = (const float*)d_in[22];
  const float* c3_b2 = (const float*)d_in[23];
  const float* c3_k  = (const float*)d_in[24];
  const float* c3_bs = (const float*)d_in[25];
  const float* bn1_g = (const float*)d_in[26];
  const float* bn1_b = (const float*)d_in[27];
  const float* bn2_g = (const float*)d_in[28];
  const float* bn2_b = (const float*)d_in[29];
  const float* bn3_g = (const float*)d_in[30];
  const float* bn3_b = (const float*)d_in[31];

  char* ws = (char*)d_ws;
  unsigned short* xTb = (unsigned short*)(ws + 0);
  unsigned short* h1  = (unsigned short*)(ws + 6422528);
  unsigned short* h2  = (unsigned short*)(ws + 19267584);
  unsigned short* h3  = (unsigned short*)(ws + 32112640);
  float* Abuf         = (float*)(ws + 57802752);
  float* gpart        = (float*)(ws + 61867008);
  unsigned short* wb1 = (unsigned short*)(ws + 65078272);
  unsigned short* wb2 = (unsigned short*)(ws + 65081344);
  unsigned short* wb3 = (unsigned short*)(ws + 65099776);
  float* sc1 = (float*)(ws + 65137664); float* sh1 = sc1 + 32;
  float* sc2 = sh1 + 32;                float* sh2 = sc2 + 32;
  float* sc3 = sh2 + 32;                float* sh3 = sc3 + 64;

  const float invN = 1.0f / (float)(N2C * 16);
  const int ablocks = (N2C * 9 + 255) / 256;

  transpose_x_kernel<<<N1C/64, 256, 0, stream>>>(x, xTb);
  wcvt_kernel<<<(32*32 + 255)/256, 256, 0, stream>>>(c1_k, wb1, 32*32, 27, 32, 0);
  wcvt_kernel<<<(32*288 + 255)/256, 256, 0, stream>>>(c2_k, wb2, 32*288, 288, 288, 1);
  wcvt_kernel<<<(64*288 + 255)/256, 256, 0, stream>>>(c3_k, wb3, 64*288, 288, 288, 1);

  // conv1
  compute_A_kernel<<<ablocks, 256, 0, stream>>>(l1, l2, knn1, c1_w1, c1_b1, c1_w2, c1_b2, Abuf);
  conv_mfma_kernel<3, 4, 32, 8, false><<<N2C/8, 256, 0, stream>>>(
      xTb, knn1, Abuf, wb1, c1_bs, nullptr, nullptr, h1, gpart);
  bn_finalize_kernel<<<32, 256, 0, stream>>>(gpart, N2C/8, 32, bn1_g, bn1_b, sc1, sh1, invN);

  // conv2
  compute_A_kernel<<<ablocks, 256, 0, stream>>>(l2, l2, knn2, c2_w1, c2_b1, c2_w2, c2_b2, Abuf);
  conv_wave_kernel<32><<<N2C/4, 256, 0, stream>>>(
      h1, knn2, Abuf, wb2, c2_bs, sc1, sh1, h2, gpart);
  bn_finalize_kernel<<<32, 256, 0, stream>>>(gpart, N2C/4, 32, bn2_g, bn2_b, sc2, sh2, invN);

  // conv3
  compute_A_kernel<<<ablocks, 256, 0, stream>>>(l2, l2, knn3, c3_w1, c3_b1, c3_w2, c3_b2, Abuf);
  conv_wave_kernel<64><<<N2C/4, 256, 0, stream>>>(
      h2, knn3, Abuf, wb3, c3_bs, sc2, sh2, h3, gpart);
  bn_finalize_kernel<<<64, 256, 0, stream>>>(gpart, N2C/4, 64, bn3_g, bn3_b, sc3, sh3, invN);

  pool_kernel<<<N3C/16, 256, 0, stream>>>(h3, pidx, sc3, sh3, (float*)d_out);
}